// Round 1
// baseline (649.570 us; speedup 1.0000x reference)
//
#include <hip/hip_runtime.h>
#include <hip/hip_bf16.h>
#include <cstdint>
#include <cstddef>

typedef unsigned short u16;
typedef short s16x8 __attribute__((ext_vector_type(8)));
typedef float f32x4 __attribute__((ext_vector_type(4)));

#define HIDDEN_C 2048
#define TSEQ 2048
#define BATCH 2
#define NHEADS 16
#define NKV 4
#define HDIM 128
#define NQKV 3072
#define BTR 4096  // BATCH*TSEQ

__device__ __forceinline__ float bf2f(u16 u) {
  union { uint32_t i; float f; } v; v.i = ((uint32_t)u) << 16; return v.f;
}
__device__ __forceinline__ u16 f2bf(float f) {
  union { float f; uint32_t i; } v; v.f = f;
  uint32_t r = v.i + 0x7fffu + ((v.i >> 16) & 1u);
  return (u16)(r >> 16);
}

#define AS1(p) ((__attribute__((address_space(1))) void*)(uintptr_t)(p))
#define AS3(p) ((__attribute__((address_space(3))) void*)(p))

// ---------------- fp32 -> bf16 convert (8 elems/thread) ----------------
__global__ void convert_x_kernel(const float* __restrict__ x, u16* __restrict__ xb) {
  int i = (blockIdx.x * blockDim.x + threadIdx.x) * 8;
  float4 a = *(const float4*)(x + i);
  float4 b = *(const float4*)(x + i + 4);
  uint4 o;
  o.x = (uint32_t)f2bf(a.x) | ((uint32_t)f2bf(a.y) << 16);
  o.y = (uint32_t)f2bf(a.z) | ((uint32_t)f2bf(a.w) << 16);
  o.z = (uint32_t)f2bf(b.x) | ((uint32_t)f2bf(b.y) << 16);
  o.w = (uint32_t)f2bf(b.z) | ((uint32_t)f2bf(b.w) << 16);
  *(uint4*)(xb + i) = o;
}

// ---------------- W [R][C] fp32 -> W^T [C][R] bf16 ----------------
__global__ void transpose_w_kernel(const float* __restrict__ in, u16* __restrict__ out,
                                   int R, int C) {
  __shared__ float tile[32][33];
  int r0 = blockIdx.y * 32, c0 = blockIdx.x * 32;
  int tx = threadIdx.x, ty = threadIdx.y;
  #pragma unroll
  for (int i = 0; i < 32; i += 8)
    tile[ty + i][tx] = in[(size_t)(r0 + ty + i) * C + c0 + tx];
  __syncthreads();
  #pragma unroll
  for (int i = 0; i < 32; i += 8)
    out[(size_t)(c0 + ty + i) * R + r0 + tx] = f2bf(tile[tx][ty + i]);
}

// ---------------- GEMM: C[M][N] = A[M][K] * BT[N][K]^T (bf16 in, OutT out) -------
// m97 structure: 128x128 tile, 4 waves (2x2), BK=32, global_load_lds width 16.
template <typename OutT>
__global__ __launch_bounds__(256) void gemm_bt_kernel(const u16* __restrict__ A,
                                                      const u16* __restrict__ BT,
                                                      OutT* __restrict__ C,
                                                      int M, int N, int K) {
  __shared__ u16 As[128 * 32];
  __shared__ u16 Bs[128 * 32];
  const int tid = threadIdx.x;
  const int wave = tid >> 6, lane = tid & 63;
  const int lr = lane & 15, lg = lane >> 4;
  const int m0 = blockIdx.y * 128, n0 = blockIdx.x * 128;
  const int wr = wave >> 1, wc = wave & 1;
  f32x4 acc[4][4];
  #pragma unroll
  for (int a = 0; a < 4; ++a)
    #pragma unroll
    for (int b = 0; b < 4; ++b) acc[a][b] = (f32x4){0.f, 0.f, 0.f, 0.f};

  for (int k0 = 0; k0 < K; k0 += 32) {
    #pragma unroll
    for (int i = 0; i < 2; ++i) {
      int c = tid + i * 256;                 // chunk 0..511 (16B each)
      int row = c >> 2, col8 = (c & 3) * 8;  // 4 chunks per 32-col row
      const u16* gA = A + (size_t)(m0 + row) * K + k0 + col8;
      const u16* gB = BT + (size_t)(n0 + row) * K + k0 + col8;
      char* lA = (char*)As + ((size_t)(wave * 64 + i * 256)) * 16;
      char* lB = (char*)Bs + ((size_t)(wave * 64 + i * 256)) * 16;
      __builtin_amdgcn_global_load_lds(AS1(gA), AS3(lA), 16, 0, 0);
      __builtin_amdgcn_global_load_lds(AS1(gB), AS3(lB), 16, 0, 0);
    }
    __syncthreads();
    s16x8 af[4], bfr[4];
    #pragma unroll
    for (int mi = 0; mi < 4; ++mi)
      af[mi] = *(const s16x8*)(As + (wr * 64 + mi * 16 + lr) * 32 + lg * 8);
    #pragma unroll
    for (int ni = 0; ni < 4; ++ni)
      bfr[ni] = *(const s16x8*)(Bs + (wc * 64 + ni * 16 + lr) * 32 + lg * 8);
    #pragma unroll
    for (int mi = 0; mi < 4; ++mi)
      #pragma unroll
      for (int ni = 0; ni < 4; ++ni)
        acc[mi][ni] = __builtin_amdgcn_mfma_f32_16x16x32_bf16(af[mi], bfr[ni], acc[mi][ni], 0, 0, 0);
    __syncthreads();
  }
  // epilogue: C/D layout col=lane&15, row=(lane>>4)*4+r
  #pragma unroll
  for (int mi = 0; mi < 4; ++mi) {
    int rowb = m0 + wr * 64 + mi * 16 + lg * 4;
    #pragma unroll
    for (int ni = 0; ni < 4; ++ni) {
      int col = n0 + wc * 64 + ni * 16 + lr;
      #pragma unroll
      for (int r = 0; r < 4; ++r) {
        float v = acc[mi][ni][r];
        if constexpr (sizeof(OutT) == 2) C[(size_t)(rowb + r) * N + col] = (OutT)f2bf(v);
        else                             C[(size_t)(rowb + r) * N + col] = v;
      }
    }
  }
}

// ---------------- RoPE (+optional scale), in-place on qkv ----------------
// thread = (bt, head, quarter of 32 dims); quarter 0 does the rotation.
__global__ void rope_kernel(u16* __restrict__ base, int col_off, int head_shift, float scale) {
  int idx = blockIdx.x * blockDim.x + threadIdx.x;
  int quarter = idx & 3;
  int hidx = idx >> 2;
  int head = hidx & ((1 << head_shift) - 1);
  int bt = hidx >> head_shift;
  if (bt >= BTR) return;
  int t = bt & (TSEQ - 1);
  u16* p = base + (size_t)bt * NQKV + col_off + head * HDIM + quarter * 32;
  uint4 u[4];
  #pragma unroll
  for (int j = 0; j < 4; ++j) u[j] = ((const uint4*)p)[j];
  float v[32];
  #pragma unroll
  for (int j = 0; j < 4; ++j) {
    v[j*8+0] = bf2f((u16)(u[j].x & 0xffff)); v[j*8+1] = bf2f((u16)(u[j].x >> 16));
    v[j*8+2] = bf2f((u16)(u[j].y & 0xffff)); v[j*8+3] = bf2f((u16)(u[j].y >> 16));
    v[j*8+4] = bf2f((u16)(u[j].z & 0xffff)); v[j*8+5] = bf2f((u16)(u[j].z >> 16));
    v[j*8+6] = bf2f((u16)(u[j].w & 0xffff)); v[j*8+7] = bf2f((u16)(u[j].w >> 16));
  }
  if (quarter == 0) {
    #pragma unroll
    for (int i = 0; i < 16; ++i) {
      float f = powf(10000.f, -(float)i * (1.f / 16.f));
      float ang = (float)t * f;
      float s = sinf(ang), c = cosf(ang);
      float a = v[i], b = v[i + 16];
      v[i]      = a * c - b * s;
      v[i + 16] = b * c + a * s;
    }
  }
  #pragma unroll
  for (int i = 0; i < 32; ++i) v[i] *= scale;
  #pragma unroll
  for (int j = 0; j < 4; ++j) {
    u[j].x = (uint32_t)f2bf(v[j*8+0]) | ((uint32_t)f2bf(v[j*8+1]) << 16);
    u[j].y = (uint32_t)f2bf(v[j*8+2]) | ((uint32_t)f2bf(v[j*8+3]) << 16);
    u[j].z = (uint32_t)f2bf(v[j*8+4]) | ((uint32_t)f2bf(v[j*8+5]) << 16);
    u[j].w = (uint32_t)f2bf(v[j*8+6]) | ((uint32_t)f2bf(v[j*8+7]) << 16);
  }
  #pragma unroll
  for (int j = 0; j < 4; ++j) ((uint4*)p)[j] = u[j];
}

// ---------------- V [b][t][g][d] -> VT [b][g][d][t] ----------------
__global__ void transpose_v_kernel(const u16* __restrict__ qkv, u16* __restrict__ vt) {
  int bg = blockIdx.z;
  int b = bg >> 2, g = bg & 3;
  int t0 = blockIdx.x * 32, d0 = blockIdx.y * 32;
  __shared__ u16 tile[32][33];
  int tx = threadIdx.x, ty = threadIdx.y;
  #pragma unroll
  for (int i = 0; i < 32; i += 8)
    tile[ty + i][tx] = qkv[(size_t)(b * TSEQ + t0 + ty + i) * NQKV + 2560 + g * HDIM + d0 + tx];
  __syncthreads();
  #pragma unroll
  for (int i = 0; i < 32; i += 8)
    vt[((size_t)bg * HDIM + d0 + ty + i) * TSEQ + t0 + tx] = tile[tx][ty + i];
}

// ---------------- flash attention ----------------
// block = 4 waves; each wave owns a 16-row Q tile; k-blocks of 32.
__global__ __launch_bounds__(256) void attn_kernel(const u16* __restrict__ qkv,
                                                   const u16* __restrict__ vt,
                                                   u16* __restrict__ attn_out) {
  const int b = blockIdx.z, h = blockIdx.y, g = h >> 2;
  const int tid = threadIdx.x, wave = tid >> 6, lane = tid & 63;
  const int lr = lane & 15, lg = lane >> 4;
  const int q0 = blockIdx.x * 64 + wave * 16;
  const u16* Qp = qkv + (size_t)b * TSEQ * NQKV + h * HDIM;
  const u16* Kp = qkv + (size_t)b * TSEQ * NQKV + HIDDEN_C + g * HDIM;
  const u16* Vt = vt + (size_t)(b * NKV + g) * HDIM * TSEQ;
  __shared__ u16 P_lds[4][16][48];

  s16x8 aq[4];
  {
    const u16* qrow = Qp + (size_t)(q0 + lr) * NQKV + lg * 8;
    #pragma unroll
    for (int kk = 0; kk < 4; ++kk) aq[kk] = *(const s16x8*)(qrow + kk * 32);
  }
  f32x4 O[8];
  #pragma unroll
  for (int d = 0; d < 8; ++d) O[d] = (f32x4){0.f, 0.f, 0.f, 0.f};
  float m_r[4], l_r[4];
  #pragma unroll
  for (int r = 0; r < 4; ++r) { m_r[r] = -1e30f; l_r[r] = 0.f; }

  const int kmax = q0 + 16;  // exclusive causal bound
  for (int kb = 0; kb < kmax; kb += 32) {
    f32x4 S0 = (f32x4){0.f,0.f,0.f,0.f}, S1 = (f32x4){0.f,0.f,0.f,0.f};
    {
      const u16* krow = Kp + (size_t)(kb + lr) * NQKV + lg * 8;
      #pragma unroll
      for (int kk = 0; kk < 4; ++kk) {
        s16x8 bk = *(const s16x8*)(krow + kk * 32);
        S0 = __builtin_amdgcn_mfma_f32_16x16x32_bf16(aq[kk], bk, S0, 0, 0, 0);
      }
    }
    const bool have1 = (kb + 16) < kmax;
    if (have1) {
      const u16* krow = Kp + (size_t)(kb + 16 + lr) * NQKV + lg * 8;
      #pragma unroll
      for (int kk = 0; kk < 4; ++kk) {
        s16x8 bk = *(const s16x8*)(krow + kk * 32);
        S1 = __builtin_amdgcn_mfma_f32_16x16x32_bf16(aq[kk], bk, S1, 0, 0, 0);
      }
    }
    if (kb + 31 >= q0) {  // causal mask (also kills unused S1 half)
      #pragma unroll
      for (int r = 0; r < 4; ++r) {
        int rr = q0 + lg * 4 + r;
        if (kb + lr > rr)      S0[r] = -1e30f;
        if (kb + 16 + lr > rr) S1[r] = -1e30f;
      }
    }
    float alpha[4];
    #pragma unroll
    for (int r = 0; r < 4; ++r) {
      float v = fmaxf(S0[r], S1[r]);
      v = fmaxf(v, __shfl_xor(v, 1));
      v = fmaxf(v, __shfl_xor(v, 2));
      v = fmaxf(v, __shfl_xor(v, 4));
      v = fmaxf(v, __shfl_xor(v, 8));
      float mn = fmaxf(m_r[r], v);
      alpha[r] = __expf(m_r[r] - mn);
      m_r[r] = mn;
      float p0 = __expf(S0[r] - mn);
      float p1 = __expf(S1[r] - mn);
      S0[r] = p0; S1[r] = p1;
      float ps = p0 + p1;
      ps += __shfl_xor(ps, 1); ps += __shfl_xor(ps, 2);
      ps += __shfl_xor(ps, 4); ps += __shfl_xor(ps, 8);
      l_r[r] = l_r[r] * alpha[r] + ps;
    }
    #pragma unroll
    for (int d = 0; d < 8; ++d)
      #pragma unroll
      for (int r = 0; r < 4; ++r) O[d][r] *= alpha[r];
    // P (scores layout) -> LDS -> A-fragment layout
    #pragma unroll
    for (int r = 0; r < 4; ++r) {
      P_lds[wave][lg * 4 + r][lr]      = f2bf(S0[r]);
      P_lds[wave][lg * 4 + r][16 + lr] = f2bf(S1[r]);
    }
    asm volatile("s_waitcnt lgkmcnt(0)" ::: "memory");
    __builtin_amdgcn_sched_barrier(0);
    s16x8 pf = *(const s16x8*)(&P_lds[wave][lr][lg * 8]);
    #pragma unroll
    for (int dt = 0; dt < 8; ++dt) {
      s16x8 bv = *(const s16x8*)(Vt + (size_t)(dt * 16 + lr) * TSEQ + kb + lg * 8);
      O[dt] = __builtin_amdgcn_mfma_f32_16x16x32_bf16(pf, bv, O[dt], 0, 0, 0);
    }
  }
  float invl[4];
  #pragma unroll
  for (int r = 0; r < 4; ++r) invl[r] = 1.f / l_r[r];
  #pragma unroll
  for (int dt = 0; dt < 8; ++dt)
    #pragma unroll
    for (int r = 0; r < 4; ++r) {
      float v = O[dt][r] * invl[r];
      attn_out[(size_t)(b * TSEQ + q0 + lg * 4 + r) * HIDDEN_C + h * HDIM + dt * 16 + lr] = f2bf(v);
    }
}

extern "C" void kernel_launch(void* const* d_in, const int* in_sizes, int n_in,
                              void* d_out, int out_size, void* d_ws, size_t ws_size,
                              hipStream_t stream) {
  const float* x  = (const float*)d_in[0];
  const float* Wq = (const float*)d_in[1];
  const float* Wk = (const float*)d_in[2];
  const float* Wv = (const float*)d_in[3];
  const float* Wo = (const float*)d_in[4];
  float* out = (float*)d_out;
  char* ws = (char*)d_ws;

  u16* xb    = (u16*)(ws);                          // 16 MiB
  u16* wqkvT = (u16*)(ws + (size_t)(16u << 20));    // 12 MiB  [3072][2048]
  u16* woT   = (u16*)(ws + (size_t)(28u << 20));    //  8 MiB  [2048][2048]
  u16* qkv   = (u16*)(ws + (size_t)(36u << 20));    // 24 MiB  [4096][3072]
  u16* vtb   = (u16*)(ws + (size_t)(60u << 20));    //  4 MiB  [2][4][128][2048]
  u16* attn  = (u16*)(ws + (size_t)(64u << 20));    // 16 MiB  [4096][2048]

  dim3 tb(32, 8);
  convert_x_kernel<<<(BTR * HIDDEN_C / 8) / 256, 256, 0, stream>>>(x, xb);
  transpose_w_kernel<<<dim3(HIDDEN_C / 32, HIDDEN_C / 32), tb, 0, stream>>>(Wq, wqkvT, HIDDEN_C, HIDDEN_C);
  transpose_w_kernel<<<dim3(512 / 32, HIDDEN_C / 32), tb, 0, stream>>>(Wk, wqkvT + (size_t)2048 * 2048, HIDDEN_C, 512);
  transpose_w_kernel<<<dim3(512 / 32, HIDDEN_C / 32), tb, 0, stream>>>(Wv, wqkvT + (size_t)2560 * 2048, HIDDEN_C, 512);
  transpose_w_kernel<<<dim3(HIDDEN_C / 32, HIDDEN_C / 32), tb, 0, stream>>>(Wo, woT, HIDDEN_C, HIDDEN_C);

  gemm_bt_kernel<u16><<<dim3(NQKV / 128, BTR / 128), 256, 0, stream>>>(xb, wqkvT, qkv, BTR, NQKV, HIDDEN_C);

  const float scale = 0.53033008588991f;  // 6/sqrt(128)
  rope_kernel<<<(BTR * NHEADS * 4) / 256, 256, 0, stream>>>(qkv, 0, 4, scale);
  rope_kernel<<<(BTR * NKV * 4) / 256, 256, 0, stream>>>(qkv, HIDDEN_C, 2, 1.0f);

  transpose_v_kernel<<<dim3(TSEQ / 32, HDIM / 32, BATCH * NKV), tb, 0, stream>>>(qkv, vtb);

  attn_kernel<<<dim3(TSEQ / 64, NHEADS, BATCH), 256, 0, stream>>>(qkv, vtb, attn);

  gemm_bt_kernel<float><<<dim3(HIDDEN_C / 128, BTR / 128), 256, 0, stream>>>(attn, woT, out, BTR, HIDDEN_C, HIDDEN_C);
}

// Round 2
// 290.925 us; speedup vs baseline: 2.2328x; 2.2328x over previous
//
#include <hip/hip_runtime.h>
#include <hip/hip_bf16.h>
#include <cstdint>
#include <cstddef>

typedef unsigned short u16;
typedef short s16x8 __attribute__((ext_vector_type(8)));
typedef float f32x4 __attribute__((ext_vector_type(4)));

#define HIDDEN_C 2048
#define TSEQ 2048
#define BATCH 2
#define NHEADS 16
#define NKV 4
#define HDIM 128
#define NQKV 3072
#define BTR 4096  // BATCH*TSEQ

__device__ __forceinline__ float bf2f(u16 u) {
  union { uint32_t i; float f; } v; v.i = ((uint32_t)u) << 16; return v.f;
}
__device__ __forceinline__ u16 f2bf(float f) {
  union { float f; uint32_t i; } v; v.f = f;
  uint32_t r = v.i + 0x7fffu + ((v.i >> 16) & 1u);
  return (u16)(r >> 16);
}

#define AS1(p) ((__attribute__((address_space(1))) void*)(uintptr_t)(p))
#define AS3(p) ((__attribute__((address_space(3))) void*)(p))

// ---------------- fp32 -> bf16 convert (8 elems/thread) ----------------
__global__ void convert_x_kernel(const float* __restrict__ x, u16* __restrict__ xb) {
  int i = (blockIdx.x * blockDim.x + threadIdx.x) * 8;
  float4 a = *(const float4*)(x + i);
  float4 b = *(const float4*)(x + i + 4);
  uint4 o;
  o.x = (uint32_t)f2bf(a.x) | ((uint32_t)f2bf(a.y) << 16);
  o.y = (uint32_t)f2bf(a.z) | ((uint32_t)f2bf(a.w) << 16);
  o.z = (uint32_t)f2bf(b.x) | ((uint32_t)f2bf(b.y) << 16);
  o.w = (uint32_t)f2bf(b.z) | ((uint32_t)f2bf(b.w) << 16);
  *(uint4*)(xb + i) = o;
}

// ---------------- W [R][C] fp32 -> W^T [C][R] bf16 ----------------
__global__ void transpose_w_kernel(const float* __restrict__ in, u16* __restrict__ out,
                                   int R, int C) {
  __shared__ float tile[32][33];
  int r0 = blockIdx.y * 32, c0 = blockIdx.x * 32;
  int tx = threadIdx.x, ty = threadIdx.y;
  #pragma unroll
  for (int i = 0; i < 32; i += 8)
    tile[ty + i][tx] = in[(size_t)(r0 + ty + i) * C + c0 + tx];
  __syncthreads();
  #pragma unroll
  for (int i = 0; i < 32; i += 8)
    out[(size_t)(c0 + ty + i) * R + r0 + tx] = f2bf(tile[tx][ty + i]);
}

// ---------------- GEMM: C[M][N] = A[M][K] * BT[N][K]^T (bf16 in, OutT out) -------
template <typename OutT>
__global__ __launch_bounds__(256) void gemm_bt_kernel(const u16* __restrict__ A,
                                                      const u16* __restrict__ BT,
                                                      OutT* __restrict__ C,
                                                      int M, int N, int K) {
  __shared__ u16 As[128 * 32];
  __shared__ u16 Bs[128 * 32];
  const int tid = threadIdx.x;
  const int wave = tid >> 6, lane = tid & 63;
  const int lr = lane & 15, lg = lane >> 4;
  const int m0 = blockIdx.y * 128, n0 = blockIdx.x * 128;
  const int wr = wave >> 1, wc = wave & 1;
  f32x4 acc[4][4];
  #pragma unroll
  for (int a = 0; a < 4; ++a)
    #pragma unroll
    for (int b = 0; b < 4; ++b) acc[a][b] = (f32x4){0.f, 0.f, 0.f, 0.f};

  for (int k0 = 0; k0 < K; k0 += 32) {
    #pragma unroll
    for (int i = 0; i < 2; ++i) {
      int c = tid + i * 256;
      int row = c >> 2, col8 = (c & 3) * 8;
      const u16* gA = A + (size_t)(m0 + row) * K + k0 + col8;
      const u16* gB = BT + (size_t)(n0 + row) * K + k0 + col8;
      char* lA = (char*)As + ((size_t)(wave * 64 + i * 256)) * 16;
      char* lB = (char*)Bs + ((size_t)(wave * 64 + i * 256)) * 16;
      __builtin_amdgcn_global_load_lds(AS1(gA), AS3(lA), 16, 0, 0);
      __builtin_amdgcn_global_load_lds(AS1(gB), AS3(lB), 16, 0, 0);
    }
    __syncthreads();
    s16x8 af[4], bfr[4];
    #pragma unroll
    for (int mi = 0; mi < 4; ++mi)
      af[mi] = *(const s16x8*)(As + (wr * 64 + mi * 16 + lr) * 32 + lg * 8);
    #pragma unroll
    for (int ni = 0; ni < 4; ++ni)
      bfr[ni] = *(const s16x8*)(Bs + (wc * 64 + ni * 16 + lr) * 32 + lg * 8);
    #pragma unroll
    for (int mi = 0; mi < 4; ++mi)
      #pragma unroll
      for (int ni = 0; ni < 4; ++ni)
        acc[mi][ni] = __builtin_amdgcn_mfma_f32_16x16x32_bf16(af[mi], bfr[ni], acc[mi][ni], 0, 0, 0);
    __syncthreads();
  }
  #pragma unroll
  for (int mi = 0; mi < 4; ++mi) {
    int rowb = m0 + wr * 64 + mi * 16 + lg * 4;
    #pragma unroll
    for (int ni = 0; ni < 4; ++ni) {
      int col = n0 + wc * 64 + ni * 16 + lr;
      #pragma unroll
      for (int r = 0; r < 4; ++r) {
        float v = acc[mi][ni][r];
        if constexpr (sizeof(OutT) == 2) C[(size_t)(rowb + r) * N + col] = (OutT)f2bf(v);
        else                             C[(size_t)(rowb + r) * N + col] = v;
      }
    }
  }
}

// ---------------- RoPE (+optional scale), in-place on qkv ----------------
__global__ void rope_kernel(u16* __restrict__ base, int col_off, int head_shift, float scale) {
  int idx = blockIdx.x * blockDim.x + threadIdx.x;
  int quarter = idx & 3;
  int hidx = idx >> 2;
  int head = hidx & ((1 << head_shift) - 1);
  int bt = hidx >> head_shift;
  if (bt >= BTR) return;
  int t = bt & (TSEQ - 1);
  u16* p = base + (size_t)bt * NQKV + col_off + head * HDIM + quarter * 32;
  uint4 u[4];
  #pragma unroll
  for (int j = 0; j < 4; ++j) u[j] = ((const uint4*)p)[j];
  float v[32];
  #pragma unroll
  for (int j = 0; j < 4; ++j) {
    v[j*8+0] = bf2f((u16)(u[j].x & 0xffff)); v[j*8+1] = bf2f((u16)(u[j].x >> 16));
    v[j*8+2] = bf2f((u16)(u[j].y & 0xffff)); v[j*8+3] = bf2f((u16)(u[j].y >> 16));
    v[j*8+4] = bf2f((u16)(u[j].z & 0xffff)); v[j*8+5] = bf2f((u16)(u[j].z >> 16));
    v[j*8+6] = bf2f((u16)(u[j].w & 0xffff)); v[j*8+7] = bf2f((u16)(u[j].w >> 16));
  }
  if (quarter == 0) {
    #pragma unroll
    for (int i = 0; i < 16; ++i) {
      float f = powf(10000.f, -(float)i * (1.f / 16.f));
      float ang = (float)t * f;
      float s = sinf(ang), c = cosf(ang);
      float a = v[i], b = v[i + 16];
      v[i]      = a * c - b * s;
      v[i + 16] = b * c + a * s;
    }
  }
  #pragma unroll
  for (int i = 0; i < 32; ++i) v[i] *= scale;
  #pragma unroll
  for (int j = 0; j < 4; ++j) {
    u[j].x = (uint32_t)f2bf(v[j*8+0]) | ((uint32_t)f2bf(v[j*8+1]) << 16);
    u[j].y = (uint32_t)f2bf(v[j*8+2]) | ((uint32_t)f2bf(v[j*8+3]) << 16);
    u[j].z = (uint32_t)f2bf(v[j*8+4]) | ((uint32_t)f2bf(v[j*8+5]) << 16);
    u[j].w = (uint32_t)f2bf(v[j*8+6]) | ((uint32_t)f2bf(v[j*8+7]) << 16);
  }
  #pragma unroll
  for (int j = 0; j < 4; ++j) ((uint4*)p)[j] = u[j];
}

// ---------------- V [b][t][g][d] -> VT [b][g][d][t] ----------------
__global__ void transpose_v_kernel(const u16* __restrict__ qkv, u16* __restrict__ vt) {
  int bg = blockIdx.z;
  int b = bg >> 2, g = bg & 3;
  int t0 = blockIdx.x * 32, d0 = blockIdx.y * 32;
  __shared__ u16 tile[32][33];
  int tx = threadIdx.x, ty = threadIdx.y;
  #pragma unroll
  for (int i = 0; i < 32; i += 8)
    tile[ty + i][tx] = qkv[(size_t)(b * TSEQ + t0 + ty + i) * NQKV + 2560 + g * HDIM + d0 + tx];
  __syncthreads();
  #pragma unroll
  for (int i = 0; i < 32; i += 8)
    vt[((size_t)bg * HDIM + d0 + ty + i) * TSEQ + t0 + tx] = tile[tx][ty + i];
}

// ---------------- flash attention v2 ----------------
// 8 waves x 32 Q-rows = 256-row Q tile per block; KVBLK=64; K/V double-buffered
// in LDS with T2 XOR swizzle via pre-swizzled global source (rule #21).
__global__ __launch_bounds__(512, 2) void attn_kernel(const u16* __restrict__ qkv,
                                                      const u16* __restrict__ vt,
                                                      u16* __restrict__ attn_out) {
  __shared__ u16 K_lds[2][64][128];   // [buf][kpos][d]   32 KB
  __shared__ u16 V_lds[2][128][64];   // [buf][d][kpos]   32 KB
  __shared__ u16 P_lds[8][32][64];    // per-wave P tile  32 KB

  const int b = blockIdx.z, h = blockIdx.y, g = h >> 2;
  const int tid = threadIdx.x, w = tid >> 6, lane = tid & 63;
  const int lr = lane & 15, lg = lane >> 4;
  const int q0 = blockIdx.x * 256;        // block's Q-tile base
  const int q0w = q0 + w * 32;            // wave's 32-row base

  const u16* Qg = qkv + (size_t)b * TSEQ * NQKV + h * HDIM;
  const u16* Kg = qkv + (size_t)b * TSEQ * NQKV + HIDDEN_C + g * HDIM;
  const u16* Vg = vt + (size_t)(b * NKV + g) * HDIM * TSEQ;

  // Q fragments in registers: rows q0w + mi*16 + lr, k = kk*32 + lg*8
  s16x8 aq[2][4];
  #pragma unroll
  for (int mi = 0; mi < 2; ++mi) {
    const u16* qrow = Qg + (size_t)(q0w + mi * 16 + lr) * NQKV + lg * 8;
    #pragma unroll
    for (int kk = 0; kk < 4; ++kk) aq[mi][kk] = *(const s16x8*)(qrow + kk * 32);
  }

  f32x4 O[2][8];
  #pragma unroll
  for (int mi = 0; mi < 2; ++mi)
    #pragma unroll
    for (int dt = 0; dt < 8; ++dt) O[mi][dt] = (f32x4){0.f, 0.f, 0.f, 0.f};
  float m_r[2][4], l_r[2][4];
  #pragma unroll
  for (int mi = 0; mi < 2; ++mi)
    #pragma unroll
    for (int r = 0; r < 4; ++r) { m_r[mi][r] = -1e30f; l_r[mi][r] = 0.f; }

  // stage K/V k-block kb into buffer `buf`; LDS linear, source pre-swizzled
  auto STAGE = [&](int buf, int kb) {
    #pragma unroll
    for (int i = 0; i < 2; ++i) {          // K: 64 rows x 16 chunks of 16B
      int c = tid + i * 512;
      int row = c >> 4, slot = c & 15;
      int gslot = slot ^ (row & 7);
      const u16* src = Kg + (size_t)(kb + row) * NQKV + gslot * 8;
      char* dst = (char*)&K_lds[buf][0][0] + (size_t)c * 16;
      __builtin_amdgcn_global_load_lds(AS1(src), AS3(dst), 16, 0, 0);
    }
    #pragma unroll
    for (int i = 0; i < 2; ++i) {          // V: 128 rows(d) x 8 chunks of 16B
      int c = tid + i * 512;
      int row = c >> 3, slot = c & 7;
      int gslot = slot ^ (row & 7);
      const u16* src = Vg + (size_t)row * TSEQ + kb + gslot * 8;
      char* dst = (char*)&V_lds[buf][0][0] + (size_t)c * 16;
      __builtin_amdgcn_global_load_lds(AS1(src), AS3(dst), 16, 0, 0);
    }
  };

  const int nt = (q0 + 256) / 64;  // causal: k < q0+256
  STAGE(0, 0);
  asm volatile("s_waitcnt vmcnt(0)" ::: "memory");
  __syncthreads();

  for (int t = 0; t < nt; ++t) {
    const int kb = t * 64;
    const int cur = t & 1;
    if (t + 1 < nt) STAGE(cur ^ 1, kb + 64);

    if (kb <= q0w + 31) {  // wave has at least one unmasked (row,col)
      // ---- QK^T: S[mi][ni] over 64 k-cols ----
      f32x4 S[2][4];
      #pragma unroll
      for (int mi = 0; mi < 2; ++mi)
        #pragma unroll
        for (int ni = 0; ni < 4; ++ni) S[mi][ni] = (f32x4){0.f, 0.f, 0.f, 0.f};
      #pragma unroll
      for (int ni = 0; ni < 4; ++ni) {
        const u16* krow = &K_lds[cur][ni * 16 + lr][0];
        #pragma unroll
        for (int kk = 0; kk < 4; ++kk) {
          s16x8 bk = *(const s16x8*)(krow + ((kk * 32 + lg * 8) ^ ((lr & 7) << 3)));
          #pragma unroll
          for (int mi = 0; mi < 2; ++mi)
            S[mi][ni] = __builtin_amdgcn_mfma_f32_16x16x32_bf16(aq[mi][kk], bk, S[mi][ni], 0, 0, 0);
        }
      }
      // ---- causal mask ----
      if (kb + 63 > q0w) {
        #pragma unroll
        for (int mi = 0; mi < 2; ++mi)
          #pragma unroll
          for (int r = 0; r < 4; ++r) {
            int rr = q0w + mi * 16 + lg * 4 + r;
            #pragma unroll
            for (int ni = 0; ni < 4; ++ni) {
              int cc = kb + ni * 16 + lr;
              if (cc > rr) S[mi][ni][r] = -1e30f;
            }
          }
      }
      // ---- online softmax (wave-parallel over 16-lane groups) ----
      float alpha[2][4];
      #pragma unroll
      for (int mi = 0; mi < 2; ++mi)
        #pragma unroll
        for (int r = 0; r < 4; ++r) {
          float v = fmaxf(fmaxf(S[mi][0][r], S[mi][1][r]), fmaxf(S[mi][2][r], S[mi][3][r]));
          v = fmaxf(v, __shfl_xor(v, 1));
          v = fmaxf(v, __shfl_xor(v, 2));
          v = fmaxf(v, __shfl_xor(v, 4));
          v = fmaxf(v, __shfl_xor(v, 8));
          float mn = fmaxf(m_r[mi][r], v);
          float al = __expf(m_r[mi][r] - mn);
          m_r[mi][r] = mn;
          float ps = 0.f;
          #pragma unroll
          for (int ni = 0; ni < 4; ++ni) {
            float p = __expf(S[mi][ni][r] - mn);
            S[mi][ni][r] = p;
            ps += p;
          }
          ps += __shfl_xor(ps, 1); ps += __shfl_xor(ps, 2);
          ps += __shfl_xor(ps, 4); ps += __shfl_xor(ps, 8);
          l_r[mi][r] = l_r[mi][r] * al + ps;
          alpha[mi][r] = al;
        }
      #pragma unroll
      for (int mi = 0; mi < 2; ++mi)
        #pragma unroll
        for (int dt = 0; dt < 8; ++dt)
          #pragma unroll
          for (int r = 0; r < 4; ++r) O[mi][dt][r] *= alpha[mi][r];
      // ---- P -> LDS (swizzled scalar writes) ----
      u16* pw = &P_lds[w][0][0];
      #pragma unroll
      for (int mi = 0; mi < 2; ++mi)
        #pragma unroll
        for (int r = 0; r < 4; ++r) {
          int qrl = mi * 16 + lg * 4 + r;
          int sw = (qrl & 7) << 3;
          #pragma unroll
          for (int ni = 0; ni < 4; ++ni)
            pw[qrl * 64 + ((ni * 16 + lr) ^ sw)] = f2bf(S[mi][ni][r]);
        }
      asm volatile("s_waitcnt lgkmcnt(0)" ::: "memory");
      __builtin_amdgcn_sched_barrier(0);
      // ---- PV ----
      s16x8 pa[2][2];
      #pragma unroll
      for (int mi = 0; mi < 2; ++mi) {
        const u16* prow = &P_lds[w][mi * 16 + lr][0];
        #pragma unroll
        for (int ks = 0; ks < 2; ++ks)
          pa[mi][ks] = *(const s16x8*)(prow + ((ks * 32 + lg * 8) ^ ((lr & 7) << 3)));
      }
      #pragma unroll
      for (int dt = 0; dt < 8; ++dt) {
        const u16* vrow = &V_lds[cur][dt * 16 + lr][0];
        #pragma unroll
        for (int ks = 0; ks < 2; ++ks) {
          s16x8 bv = *(const s16x8*)(vrow + ((ks * 32 + lg * 8) ^ ((lr & 7) << 3)));
          #pragma unroll
          for (int mi = 0; mi < 2; ++mi)
            O[mi][dt] = __builtin_amdgcn_mfma_f32_16x16x32_bf16(pa[mi][ks], bv, O[mi][dt], 0, 0, 0);
        }
      }
    }
    asm volatile("s_waitcnt vmcnt(0)" ::: "memory");
    __syncthreads();
  }

  float invl[2][4];
  #pragma unroll
  for (int mi = 0; mi < 2; ++mi)
    #pragma unroll
    for (int r = 0; r < 4; ++r) invl[mi][r] = 1.f / l_r[mi][r];
  #pragma unroll
  for (int mi = 0; mi < 2; ++mi)
    #pragma unroll
    for (int dt = 0; dt < 8; ++dt)
      #pragma unroll
      for (int r = 0; r < 4; ++r) {
        float v = O[mi][dt][r] * invl[mi][r];
        attn_out[(size_t)(b * TSEQ + q0w + mi * 16 + lg * 4 + r) * HIDDEN_C + h * HDIM + dt * 16 + lr] = f2bf(v);
      }
}

extern "C" void kernel_launch(void* const* d_in, const int* in_sizes, int n_in,
                              void* d_out, int out_size, void* d_ws, size_t ws_size,
                              hipStream_t stream) {
  const float* x  = (const float*)d_in[0];
  const float* Wq = (const float*)d_in[1];
  const float* Wk = (const float*)d_in[2];
  const float* Wv = (const float*)d_in[3];
  const float* Wo = (const float*)d_in[4];
  float* out = (float*)d_out;
  char* ws = (char*)d_ws;

  u16* xb    = (u16*)(ws);                          // 16 MiB
  u16* wqkvT = (u16*)(ws + (size_t)(16u << 20));    // 12 MiB  [3072][2048]
  u16* woT   = (u16*)(ws + (size_t)(28u << 20));    //  8 MiB  [2048][2048]
  u16* qkv   = (u16*)(ws + (size_t)(36u << 20));    // 24 MiB  [4096][3072]
  u16* vtb   = (u16*)(ws + (size_t)(60u << 20));    //  4 MiB  [2][4][128][2048]
  u16* attn  = (u16*)(ws + (size_t)(64u << 20));    // 16 MiB  [4096][2048]

  dim3 tb(32, 8);
  convert_x_kernel<<<(BTR * HIDDEN_C / 8) / 256, 256, 0, stream>>>(x, xb);
  transpose_w_kernel<<<dim3(HIDDEN_C / 32, HIDDEN_C / 32), tb, 0, stream>>>(Wq, wqkvT, HIDDEN_C, HIDDEN_C);
  transpose_w_kernel<<<dim3(512 / 32, HIDDEN_C / 32), tb, 0, stream>>>(Wk, wqkvT + (size_t)2048 * 2048, HIDDEN_C, 512);
  transpose_w_kernel<<<dim3(512 / 32, HIDDEN_C / 32), tb, 0, stream>>>(Wv, wqkvT + (size_t)2560 * 2048, HIDDEN_C, 512);
  transpose_w_kernel<<<dim3(HIDDEN_C / 32, HIDDEN_C / 32), tb, 0, stream>>>(Wo, woT, HIDDEN_C, HIDDEN_C);

  gemm_bt_kernel<u16><<<dim3(NQKV / 128, BTR / 128), 256, 0, stream>>>(xb, wqkvT, qkv, BTR, NQKV, HIDDEN_C);

  const float scale = 0.53033008588991f;  // 6/sqrt(128)
  rope_kernel<<<(BTR * NHEADS * 4) / 256, 256, 0, stream>>>(qkv, 0, 4, scale);
  rope_kernel<<<(BTR * NKV * 4) / 256, 256, 0, stream>>>(qkv, HIDDEN_C, 2, 1.0f);

  transpose_v_kernel<<<dim3(TSEQ / 32, HDIM / 32, BATCH * NKV), tb, 0, stream>>>(qkv, vtb);

  attn_kernel<<<dim3(TSEQ / 256, NHEADS, BATCH), 512, 0, stream>>>(qkv, vtb, attn);

  gemm_bt_kernel<float><<<dim3(HIDDEN_C / 128, BTR / 128), 256, 0, stream>>>(attn, woT, out, BTR, HIDDEN_C, HIDDEN_C);
}